// Round 7
// baseline (91.558 us; speedup 1.0000x reference)
//
#include <hip/hip_runtime.h>

constexpr int V  = 50257;   // vocab
constexpr int D  = 300;     // vocab dim
constexpr int KD = 512;     // decoder dim
constexpr int B  = 16;      // batch

constexpr int ROWS = 64;                      // rows per k_att block
constexpr int NB_ATT = (V + ROWS - 1) / ROWS; // 786 blocks
constexpr int NT = 5;                         // 5 d-tiles of 64 (D padded 320)
constexpr int NC  = 512;                      // wsum chunks
constexpr int RPC = (V + NC - 1) / NC;        // 99 rows per chunk

constexpr float NEG_HUGE = -1.0e30f;

// ws layout (float offsets)
constexpr size_t WS_QT   = 0;                              // 4800
constexpr size_t WS_STAT = 4800;                           // NB_ATT*32
constexpr size_t WS_MS   = WS_STAT + (size_t)NB_ATT * 32;  // 32
constexpr size_t WS_PART = WS_MS + 32;                     // NC*4800
constexpr size_t WS_TMP  = WS_PART + (size_t)NC * 4800;    // 16*4800

struct f4 { float v[4]; };
__device__ __forceinline__ f4 ld4(const float* p) {
    float4 t = *(const float4*)p;
    return {t.x, t.y, t.z, t.w};
}

#define AS1 __attribute__((address_space(1)))
#define AS3 __attribute__((address_space(3)))
#define DPPF(x, CTRL) __int_as_float(__builtin_amdgcn_mov_dpp(__float_as_int(x), (CTRL), 0xF, 0xF, false))

// ---------------------------------------------------------------------------
// K1: q_t[d*16+b] = sum_k dh[b,k]*Wdec[d,k] + bdec[d].  One wave per output.
__global__ void __launch_bounds__(256) k_query(
    const float* __restrict__ dh, const float* __restrict__ Wdec,
    const float* __restrict__ bdec, float* __restrict__ q_t)
{
    int wid  = (blockIdx.x * 256 + threadIdx.x) >> 6;
    int lane = threadIdx.x & 63;
    if (wid >= D * B) return;
    int d = wid >> 4, b = wid & 15;
    const float* wrow = Wdec + (size_t)d * KD;
    const float* hrow = dh + (size_t)b * KD;
    float s = 0.f;
    for (int k = lane; k < KD; k += 64) s += wrow[k] * hrow[k];
    #pragma unroll
    for (int off = 32; off; off >>= 1) s += __shfl_down(s, off, 64);
    if (lane == 0) q_t[d * 16 + b] = s + bdec[d];
}

// ---------------------------------------------------------------------------
// K2: att[b,v] = sum_d relu(E[v,d]+q[b,d])*wf[d] + bf.
// Block = 64 rows, 256 threads. Thread (slot=t&15, rg=t>>4): rows rg+16j
// (j=0..3), d-slice slot*4..+3 within each 64-d tile, ALL 16 batches.
// E staged via global_load_lds, 3 LDS bufs, counted vmcnt(4) pipeline.
// sq XOR-swizzled so every b128 read is phase-conflict-free.
// Epilogue: thread with slot>>2 == j owns row j (each (row,batch) written
// and counted in softmax stats EXACTLY ONCE — r6 counted rows 4x).
__global__ void __launch_bounds__(256) k_att(
    const float* __restrict__ E, const float* __restrict__ q_t,
    const float* __restrict__ wf, const float* __restrict__ bf,
    float* __restrict__ att, float* __restrict__ blkstats)
{
    __shared__ float se[3 * 4096];   // 48KB: 3 bufs x 64 rows x 64 d (linear)
    __shared__ float sq[5120];       // 20KB: swizzled q, 320 d x 16 b
    __shared__ float sw[320];

    const int t    = threadIdx.x;
    const int slot = t & 15;
    const int rg   = t >> 4;         // 0..15
    const int s4   = slot << 2;
    const int v0   = blockIdx.x * ROWS;

    // stage q swizzled: logical (d, bq) quad -> physical quad
    // P = (d>>1)*8 + ((((d&1)<<2)|bq) ^ ((d>>2)&7))   (bijective)
    for (int i = t; i < 5120; i += 256) {
        int d = i >> 4, b = i & 15;
        int bq = b >> 2, bl = b & 3;
        float v = (d < D) ? q_t[d * 16 + b] : 0.f;
        int P = (d >> 1) * 8 + ((((d & 1) << 2) | bq) ^ ((d >> 2) & 7));
        sq[P * 4 + bl] = v;
    }
    for (int i = t; i < 320; i += 256) sw[i] = (i < D) ? wf[i] : 0.f;

    // per-thread sq read offsets (d = tile*64 + slot*4 + i):
    // addr = tile*1024 + (i>>1)*32 + slot*64 + 4*((((i&1)<<2)|bq)^(slot&7))
    int xq[2][4];
    #pragma unroll
    for (int i1 = 0; i1 < 2; ++i1)
        #pragma unroll
        for (int bq = 0; bq < 4; ++bq)
            xq[i1][bq] = slot * 64 + 4 * ((((i1 << 2) | bq)) ^ (slot & 7));

    float acc[4][16];
    #pragma unroll
    for (int j = 0; j < 4; ++j)
        #pragma unroll
        for (int b = 0; b < 16; ++b) acc[j][b] = 0.f;

    __syncthreads();   // sq/sw visible to all waves

#define STAGE(TT, BI) do {                                                    \
    int dd = (TT) * 64 + s4;                                                  \
    if (dd >= D) dd = 0;   /* pad slice: w=0 kills it */                      \
    _Pragma("unroll")                                                         \
    for (int jj = 0; jj < 4; ++jj) {                                          \
        int row = v0 + jj * 16 + rg;                                          \
        if (row >= V) row = V - 1;                                            \
        const float* src = E + (size_t)row * D + dd;                          \
        float* lb = se + (BI) * 4096 + jj * 1024 + (t << 2);                  \
        __builtin_amdgcn_global_load_lds((const AS1 void*)src,                \
                                         (AS3 void*)lb, 16, 0, 0);            \
    }                                                                         \
} while (0)

#define COMPUTE(TT, BI) do {                                                  \
    const float* buf = se + (BI) * 4096;                                      \
    f4 ej[4];                                                                 \
    _Pragma("unroll")                                                         \
    for (int j = 0; j < 4; ++j) ej[j] = ld4(buf + rg * 64 + j * 1024 + s4);   \
    f4 wv = ld4(sw + (TT) * 64 + s4);                                         \
    const float* sqt = sq + (TT) * 1024;                                      \
    _Pragma("unroll")                                                         \
    for (int i = 0; i < 4; ++i) {                                             \
        float wi = wv.v[i];                                                   \
        _Pragma("unroll")                                                     \
        for (int bq = 0; bq < 4; ++bq) {                                      \
            f4 qv = ld4(sqt + (i >> 1) * 32 + xq[i & 1][bq]);                 \
            _Pragma("unroll")                                                 \
            for (int j = 0; j < 4; ++j) {                                     \
                float e = ej[j].v[i];                                         \
                _Pragma("unroll")                                             \
                for (int bl = 0; bl < 4; ++bl)                                \
                    acc[j][bq * 4 + bl] =                                     \
                        fmaf(fmaxf(e + qv.v[bl], 0.f), wi,                    \
                             acc[j][bq * 4 + bl]);                            \
            }                                                                 \
        }                                                                     \
    }                                                                         \
} while (0)

    STAGE(0, 0);
    STAGE(1, 1);
    for (int tt = 0; tt < NT; ++tt) {
        __builtin_amdgcn_sched_barrier(0);
        if (tt < NT - 1) asm volatile("s_waitcnt vmcnt(4)" ::: "memory");
        else             asm volatile("s_waitcnt vmcnt(0)" ::: "memory");
        __builtin_amdgcn_s_barrier();
        __builtin_amdgcn_sched_barrier(0);
        if (tt + 2 < NT) STAGE(tt + 2, (tt + 2) % 3);
        COMPUTE(tt, tt % 3);
    }
#undef STAGE
#undef COMPUTE

    // ---- reduce over 16 slots per (row, batch) ----
    // levels 1,2 (slot bits 0,1) via DPP quad_perm on the VALU pipe
    #pragma unroll
    for (int j = 0; j < 4; ++j)
        #pragma unroll
        for (int b = 0; b < 16; ++b) {
            float x = acc[j][b];
            x += DPPF(x, 0xB1);   // xor 1
            x += DPPF(x, 0x4E);   // xor 2
            acc[j][b] = x;
        }
    // compact: lane keeps batches {4c..4c+3}, c = slot&3 (static indices)
    const int c = slot & 3;
    float kept[4][4];
    #pragma unroll
    for (int j = 0; j < 4; ++j)
        #pragma unroll
        for (int kk = 0; kk < 4; ++kk) {
            float x = (c == 0) ? acc[j][kk]
                    : (c == 1) ? acc[j][4 + kk]
                    : (c == 2) ? acc[j][8 + kk]
                    :            acc[j][12 + kk];
            x += __shfl_xor(x, 4, 64);   // slot bit 2
            x += __shfl_xor(x, 8, 64);   // slot bit 3
            kept[j][kk] = x;
        }

    __syncthreads();                 // all COMPUTE reads of se done -> reuse
    float* smsM = se;                // [64 g][16 b]
    float* smsS = se + 1024;

    const float bfull = bf[0];
    const int g = (t >> 6) * 16 + (rg & 3) * 4 + (slot >> 2);   // 0..63
    const int jown = slot >> 2;      // this thread owns row j = jown
    const int rowown = v0 + rg + 16 * jown;
    const bool okown = rowown < V;

    #pragma unroll
    for (int kk = 0; kk < 4; ++kk) {
        const int b = 4 * c + kk;
        float x = ((jown == 0) ? kept[0][kk] : (jown == 1) ? kept[1][kk]
                 : (jown == 2) ? kept[2][kk] : kept[3][kk]) + bfull;
        if (okown) att[(size_t)b * V + rowown] = x;
        smsM[g * 16 + b] = okown ? x : NEG_HUGE;   // single-row partial
        smsS[g * 16 + b] = okown ? 1.f : 0.f;      // s = exp(x - m) = 1
    }
    __syncthreads();
    if (t < 64) {                    // merge 16 groups each (all distinct rows)
        int b = t & 15, q4 = t >> 4;
        float m = NEG_HUGE, s = 0.f;
        for (int u = 0; u < 16; ++u) {
            int gg = q4 * 16 + u;
            float mg = smsM[gg * 16 + b], sg = smsS[gg * 16 + b];
            float mn = fmaxf(m, mg);
            s = s * __expf(m - mn) + sg * __expf(mg - mn);
            m = mn;
        }
        se[2048 + q4 * 16 + b] = m;
        se[2112 + q4 * 16 + b] = s;
    }
    __syncthreads();
    if (t < 16) {
        float m = NEG_HUGE, s = 0.f;
        #pragma unroll
        for (int q4 = 0; q4 < 4; ++q4) {
            float mg = se[2048 + q4 * 16 + t], sg = se[2112 + q4 * 16 + t];
            float mn = fmaxf(m, mg);
            s = s * __expf(m - mn) + sg * __expf(mg - mn);
            m = mn;
        }
        blkstats[((size_t)blockIdx.x * 16 + t) * 2]     = m;
        blkstats[((size_t)blockIdx.x * 16 + t) * 2 + 1] = s;
    }
}

// ---------------------------------------------------------------------------
// K3: combine per-block stats -> M_b, 1/S_b
__global__ void __launch_bounds__(64) k_combine(
    const float* __restrict__ blkstats, float* __restrict__ MS)
{
    int b = blockIdx.x, lane = threadIdx.x;
    float m = NEG_HUGE;
    for (int cc = lane; cc < NB_ATT; cc += 64)
        m = fmaxf(m, blkstats[(size_t)(cc * 16 + b) * 2]);
    #pragma unroll
    for (int off = 32; off; off >>= 1) m = fmaxf(m, __shfl_xor(m, off, 64));
    float s = 0.f;
    for (int cc = lane; cc < NB_ATT; cc += 64)
        s += blkstats[(size_t)(cc * 16 + b) * 2 + 1] *
             __expf(blkstats[(size_t)(cc * 16 + b) * 2] - m);
    #pragma unroll
    for (int off = 32; off; off >>= 1) s += __shfl_xor(s, off, 64);
    if (lane == 0) { MS[b * 2] = m; MS[b * 2 + 1] = 1.f / s; }
}

// ---------------------------------------------------------------------------
// K4 (fused alpha + wsum): per chunk c of RPC rows:
//   phase 1: alpha = exp(att-M)*invS, written in place AND staged in LDS
//   phase 2: thread t<300 owns column d=t, accumulates 16 batch partials.
__global__ void __launch_bounds__(320) k_awsum(
    const float* __restrict__ E, float* __restrict__ att,
    const float* __restrict__ MS, float* __restrict__ partials)
{
    __shared__ float sal[RPC * 16];   // [vv][b]
    int c = blockIdx.x, t = threadIdx.x;
    int v0 = c * RPC;
    int n = V - v0;
    if (n > RPC) n = RPC;
    if (n < 0) n = 0;

    for (int i = t; i < RPC * 16; i += 320) {
        int b = i / RPC, vv = i - b * RPC;
        float a = 0.f;
        if (vv < n) {
            float M = MS[b * 2], invS = MS[b * 2 + 1];
            size_t gi = (size_t)b * V + v0 + vv;
            a = __expf(att[gi] - M) * invS;
            att[gi] = a;
        }
        sal[vv * 16 + b] = a;
    }
    __syncthreads();

    if (t < D) {
        float acc[16];
        #pragma unroll
        for (int b = 0; b < 16; ++b) acc[b] = 0.f;
        #pragma unroll 4
        for (int vv = 0; vv < n; ++vv) {
            float e = E[(size_t)(v0 + vv) * D + t];
            const float* ap = sal + vv * 16;
            f4 a0 = ld4(ap), a1 = ld4(ap + 4), a2 = ld4(ap + 8), a3 = ld4(ap + 12);
            #pragma unroll
            for (int b = 0; b < 4; ++b) {
                acc[b]      = fmaf(a0.v[b], e, acc[b]);
                acc[b + 4]  = fmaf(a1.v[b], e, acc[b + 4]);
                acc[b + 8]  = fmaf(a2.v[b], e, acc[b + 8]);
                acc[b + 12] = fmaf(a3.v[b], e, acc[b + 12]);
            }
        }
        #pragma unroll
        for (int b = 0; b < 16; ++b)
            partials[(size_t)c * 4800 + b * D + t] = acc[b];
    }
}

// ---------------------------------------------------------------------------
// K5/K6: two-stage reduction of partials over NC chunks, float4-wide.
__global__ void __launch_bounds__(256) k_red1(
    const float* __restrict__ partials, float* __restrict__ tmp)
{
    int o4 = blockIdx.x * 256 + threadIdx.x;   // quad index, 1200 total
    if (o4 >= 1200) return;
    int y = blockIdx.y;
    float4 s = {0.f, 0.f, 0.f, 0.f};
    for (int c = y * 32; c < y * 32 + 32; ++c) {
        float4 p = *(const float4*)(partials + (size_t)c * 4800 + o4 * 4);
        s.x += p.x; s.y += p.y; s.z += p.z; s.w += p.w;
    }
    *(float4*)(tmp + (size_t)y * 4800 + o4 * 4) = s;
}

__global__ void __launch_bounds__(256) k_red2(
    const float* __restrict__ tmp, float* __restrict__ out)
{
    int o4 = blockIdx.x * 256 + threadIdx.x;
    if (o4 >= 1200) return;
    float4 s = {0.f, 0.f, 0.f, 0.f};
    #pragma unroll
    for (int y = 0; y < 16; ++y) {
        float4 p = *(const float4*)(tmp + (size_t)y * 4800 + o4 * 4);
        s.x += p.x; s.y += p.y; s.z += p.z; s.w += p.w;
    }
    *(float4*)(out + o4 * 4) = s;
}

// ---------------------------------------------------------------------------
extern "C" void kernel_launch(void* const* d_in, const int* in_sizes, int n_in,
                              void* d_out, int out_size, void* d_ws, size_t ws_size,
                              hipStream_t stream) {
    const float* dh   = (const float*)d_in[0];
    const float* E    = (const float*)d_in[1];
    const float* Wdec = (const float*)d_in[2];
    const float* bdec = (const float*)d_in[3];
    const float* wf   = (const float*)d_in[4];
    const float* bf   = (const float*)d_in[5];
    float* out = (float*)d_out;          // enc [0,4800), alpha [4800, ...)
    float* ws  = (float*)d_ws;

    float* q_t   = ws + WS_QT;
    float* stats = ws + WS_STAT;
    float* MS    = ws + WS_MS;
    float* part  = ws + WS_PART;
    float* tmp   = ws + WS_TMP;
    float* att   = out + 4800;

    k_query<<<(D * B + 3) / 4, 256, 0, stream>>>(dh, Wdec, bdec, q_t);
    k_att<<<NB_ATT, 256, 0, stream>>>(E, q_t, wf, bf, att, stats);
    k_combine<<<B, 64, 0, stream>>>(stats, MS);
    k_awsum<<<NC, 320, 0, stream>>>(E, att, MS, part);
    k_red1<<<dim3(5, 16), 256, 0, stream>>>(part, tmp);
    k_red2<<<5, 256, 0, stream>>>(tmp, out);
}

// Round 8
// 87.109 us; speedup vs baseline: 1.0511x; 1.0511x over previous
//
#include <hip/hip_runtime.h>

constexpr int V  = 50257;   // vocab
constexpr int D  = 300;     // vocab dim
constexpr int KD = 512;     // decoder dim
constexpr int B  = 16;      // batch

constexpr int ROWS = 64;                      // rows per k_att block
constexpr int NB_ATT = (V + ROWS - 1) / ROWS; // 786 blocks
constexpr int NT = 5;                         // 5 d-tiles of 64 (D padded 320)
constexpr int NC  = 512;                      // wsum chunks
constexpr int RPC = (V + NC - 1) / NC;        // 99 rows per chunk

constexpr float NEG_HUGE = -1.0e30f;

// ws layout (float offsets)
constexpr size_t WS_QT   = 0;                              // 4800
constexpr size_t WS_STAT = 4800;                           // NB_ATT*32
constexpr size_t WS_MS   = WS_STAT + (size_t)NB_ATT * 32;  // 32
constexpr size_t WS_PART = WS_MS + 32;                     // NC*4800
constexpr size_t WS_TMP  = WS_PART + (size_t)NC * 4800;    // 16*4800

struct f4 { float v[4]; };
__device__ __forceinline__ f4 ld4(const float* p) {
    float4 t = *(const float4*)p;
    return {t.x, t.y, t.z, t.w};
}

#define AS1 __attribute__((address_space(1)))
#define AS3 __attribute__((address_space(3)))
#define DPPF(x, CTRL) __int_as_float(__builtin_amdgcn_mov_dpp(__float_as_int(x), (CTRL), 0xF, 0xF, false))

// ---------------------------------------------------------------------------
// K1: q_t[d*16+b] = sum_k dh[b,k]*Wdec[d,k] + bdec[d].  One wave per output.
__global__ void __launch_bounds__(256) k_query(
    const float* __restrict__ dh, const float* __restrict__ Wdec,
    const float* __restrict__ bdec, float* __restrict__ q_t)
{
    int wid  = (blockIdx.x * 256 + threadIdx.x) >> 6;
    int lane = threadIdx.x & 63;
    if (wid >= D * B) return;
    int d = wid >> 4, b = wid & 15;
    const float* wrow = Wdec + (size_t)d * KD;
    const float* hrow = dh + (size_t)b * KD;
    float s = 0.f;
    for (int k = lane; k < KD; k += 64) s += wrow[k] * hrow[k];
    #pragma unroll
    for (int off = 32; off; off >>= 1) s += __shfl_down(s, off, 64);
    if (lane == 0) q_t[d * 16 + b] = s + bdec[d];
}

// ---------------------------------------------------------------------------
// K2: att[b,v] = sum_d relu(E[v,d]+q[b,d])*wf[d] + bf.
// Block = 64 rows, 256 threads, 3 blocks/CU (LDS 53KB). Thread (slot=t&15,
// rg=t>>4): rows rg+16j (j=0..3), d-slice slot*4..+3 per 64-d tile, 16 b.
// 2-buffer pipeline: STAGE(t+1) issued BEFORE COMPUTE(t); one vmcnt(0)+
// barrier per tile (T3 minimum recipe). w in registers. sq XOR-swizzled.
__global__ void __launch_bounds__(256, 3) k_att(
    const float* __restrict__ E, const float* __restrict__ q_t,
    const float* __restrict__ wf, const float* __restrict__ bf,
    float* __restrict__ att, float* __restrict__ blkstats)
{
    __shared__ float se[2 * 4096];   // 32KB: 2 bufs x 64 rows x 64 d (linear)
    __shared__ float sq[5120];       // 20KB: swizzled q, 320 d x 16 b

    const int t    = threadIdx.x;
    const int slot = t & 15;
    const int rg   = t >> 4;         // 0..15
    const int s4   = slot << 2;
    const int v0   = blockIdx.x * ROWS;

    // stage q swizzled: P = (d>>1)*8 + ((((d&1)<<2)|bq) ^ ((d>>2)&7))
    for (int i = t; i < 5120; i += 256) {
        int d = i >> 4, b = i & 15;
        int bq = b >> 2, bl = b & 3;
        float v = (d < D) ? q_t[d * 16 + b] : 0.f;
        int P = (d >> 1) * 8 + ((((d & 1) << 2) | bq) ^ ((d >> 2) & 7));
        sq[P * 4 + bl] = v;
    }

    // w in registers: wreg[k] covers d = k*64 + s4 .. +3 (0 beyond D)
    f4 wreg[NT];
    #pragma unroll
    for (int k = 0; k < NT; ++k)
        #pragma unroll
        for (int i = 0; i < 4; ++i) {
            int d = k * 64 + s4 + i;
            wreg[k].v[i] = (d < D) ? wf[d] : 0.f;
        }

    // per-thread sq read offsets
    int xq[2][4];
    #pragma unroll
    for (int i1 = 0; i1 < 2; ++i1)
        #pragma unroll
        for (int bq = 0; bq < 4; ++bq)
            xq[i1][bq] = slot * 64 + 4 * ((((i1 << 2) | bq)) ^ (slot & 7));

    float acc[4][16];
    #pragma unroll
    for (int j = 0; j < 4; ++j)
        #pragma unroll
        for (int b = 0; b < 16; ++b) acc[j][b] = 0.f;

#define STAGE(TT, BI) do {                                                    \
    int dd = (TT) * 64 + s4;                                                  \
    if (dd >= D) dd = 0;   /* pad slice: w=0 kills it */                      \
    _Pragma("unroll")                                                         \
    for (int jj = 0; jj < 4; ++jj) {                                          \
        int row = v0 + jj * 16 + rg;                                          \
        if (row >= V) row = V - 1;                                            \
        const float* src = E + (size_t)row * D + dd;                          \
        float* lb = se + (BI) * 4096 + jj * 1024 + (t << 2);                  \
        __builtin_amdgcn_global_load_lds((const AS1 void*)src,                \
                                         (AS3 void*)lb, 16, 0, 0);            \
    }                                                                         \
} while (0)

#define COMPUTE(TT, BI) do {                                                  \
    const float* buf = se + (BI) * 4096;                                      \
    f4 ej[4];                                                                 \
    _Pragma("unroll")                                                         \
    for (int j = 0; j < 4; ++j) ej[j] = ld4(buf + j * 1024 + (t << 2));       \
    const float* sqt = sq + (TT) * 1024;                                      \
    _Pragma("unroll")                                                         \
    for (int i = 0; i < 4; ++i) {                                             \
        float wi = wreg[TT].v[i];                                             \
        _Pragma("unroll")                                                     \
        for (int bq = 0; bq < 4; ++bq) {                                      \
            f4 qv = ld4(sqt + (i >> 1) * 32 + xq[i & 1][bq]);                 \
            _Pragma("unroll")                                                 \
            for (int j = 0; j < 4; ++j) {                                     \
                float e = ej[j].v[i];                                         \
                _Pragma("unroll")                                             \
                for (int bl = 0; bl < 4; ++bl)                                \
                    acc[j][bq * 4 + bl] =                                     \
                        fmaf(fmaxf(e + qv.v[bl], 0.f), wi,                    \
                             acc[j][bq * 4 + bl]);                            \
            }                                                                 \
        }                                                                     \
    }                                                                         \
} while (0)

    STAGE(0, 0);
    asm volatile("s_waitcnt vmcnt(0)" ::: "memory");
    __syncthreads();                 // q/w staged + buf0 ready

    #pragma unroll
    for (int tt = 0; tt < NT; ++tt) {
        if (tt + 1 < NT) STAGE(tt + 1, (tt + 1) & 1);
        COMPUTE(tt, tt & 1);
        asm volatile("s_waitcnt vmcnt(0)" ::: "memory");
        __builtin_amdgcn_s_barrier();
        __builtin_amdgcn_sched_barrier(0);
    }
#undef STAGE
#undef COMPUTE

    // ---- reduce over 16 slots per (row, batch) ----
    #pragma unroll
    for (int j = 0; j < 4; ++j)
        #pragma unroll
        for (int b = 0; b < 16; ++b) {
            float x = acc[j][b];
            x += DPPF(x, 0xB1);   // xor 1
            x += DPPF(x, 0x4E);   // xor 2
            acc[j][b] = x;
        }
    const int c = slot & 3;
    float kept[4][4];
    #pragma unroll
    for (int j = 0; j < 4; ++j)
        #pragma unroll
        for (int kk = 0; kk < 4; ++kk) {
            float x = (c == 0) ? acc[j][kk]
                    : (c == 1) ? acc[j][4 + kk]
                    : (c == 2) ? acc[j][8 + kk]
                    :            acc[j][12 + kk];
            x += __shfl_xor(x, 4, 64);   // slot bit 2
            x += __shfl_xor(x, 8, 64);   // slot bit 3
            kept[j][kk] = x;
        }

    __syncthreads();                 // se free for reuse
    float* smsM = se;                // [64 g][16 b]
    float* smsS = se + 1024;

    const float bfull = bf[0];
    const int g = (t >> 6) * 16 + (rg & 3) * 4 + (slot >> 2);   // 0..63
    const int jown = slot >> 2;      // this thread owns row j = jown
    const int rowown = v0 + rg + 16 * jown;
    const bool okown = rowown < V;

    #pragma unroll
    for (int kk = 0; kk < 4; ++kk) {
        const int b = 4 * c + kk;
        float x = ((jown == 0) ? kept[0][kk] : (jown == 1) ? kept[1][kk]
                 : (jown == 2) ? kept[2][kk] : kept[3][kk]) + bfull;
        if (okown) att[(size_t)b * V + rowown] = x;
        smsM[g * 16 + b] = okown ? x : NEG_HUGE;   // single-row partial
        smsS[g * 16 + b] = okown ? 1.f : 0.f;
    }
    __syncthreads();
    if (t < 64) {                    // merge 16 groups each (distinct rows)
        int b = t & 15, q4 = t >> 4;
        float m = NEG_HUGE, s = 0.f;
        for (int u = 0; u < 16; ++u) {
            int gg = q4 * 16 + u;
            float mg = smsM[gg * 16 + b], sg = smsS[gg * 16 + b];
            float mn = fmaxf(m, mg);
            s = s * __expf(m - mn) + sg * __expf(mg - mn);
            m = mn;
        }
        se[2048 + q4 * 16 + b] = m;
        se[2112 + q4 * 16 + b] = s;
    }
    __syncthreads();
    if (t < 16) {
        float m = NEG_HUGE, s = 0.f;
        #pragma unroll
        for (int q4 = 0; q4 < 4; ++q4) {
            float mg = se[2048 + q4 * 16 + t], sg = se[2112 + q4 * 16 + t];
            float mn = fmaxf(m, mg);
            s = s * __expf(m - mn) + sg * __expf(mg - mn);
            m = mn;
        }
        blkstats[((size_t)blockIdx.x * 16 + t) * 2]     = m;
        blkstats[((size_t)blockIdx.x * 16 + t) * 2 + 1] = s;
    }
}

// ---------------------------------------------------------------------------
// K3: combine per-block stats -> M_b, 1/S_b
__global__ void __launch_bounds__(64) k_combine(
    const float* __restrict__ blkstats, float* __restrict__ MS)
{
    int b = blockIdx.x, lane = threadIdx.x;
    float m = NEG_HUGE;
    for (int cc = lane; cc < NB_ATT; cc += 64)
        m = fmaxf(m, blkstats[(size_t)(cc * 16 + b) * 2]);
    #pragma unroll
    for (int off = 32; off; off >>= 1) m = fmaxf(m, __shfl_xor(m, off, 64));
    float s = 0.f;
    for (int cc = lane; cc < NB_ATT; cc += 64)
        s += blkstats[(size_t)(cc * 16 + b) * 2 + 1] *
             __expf(blkstats[(size_t)(cc * 16 + b) * 2] - m);
    #pragma unroll
    for (int off = 32; off; off >>= 1) s += __shfl_xor(s, off, 64);
    if (lane == 0) { MS[b * 2] = m; MS[b * 2 + 1] = 1.f / s; }
}

// ---------------------------------------------------------------------------
// K4 (fused alpha + wsum): per chunk c of RPC rows:
//   phase 1: alpha = exp(att-M)*invS, written in place AND staged in LDS
//   phase 2: thread t<300 owns column d=t, accumulates 16 batch partials.
__global__ void __launch_bounds__(320) k_awsum(
    const float* __restrict__ E, float* __restrict__ att,
    const float* __restrict__ MS, float* __restrict__ partials)
{
    __shared__ float sal[RPC * 16];   // [vv][b]
    int c = blockIdx.x, t = threadIdx.x;
    int v0 = c * RPC;
    int n = V - v0;
    if (n > RPC) n = RPC;
    if (n < 0) n = 0;

    for (int i = t; i < RPC * 16; i += 320) {
        int b = i / RPC, vv = i - b * RPC;
        float a = 0.f;
        if (vv < n) {
            float M = MS[b * 2], invS = MS[b * 2 + 1];
            size_t gi = (size_t)b * V + v0 + vv;
            a = __expf(att[gi] - M) * invS;
            att[gi] = a;
        }
        sal[vv * 16 + b] = a;
    }
    __syncthreads();

    if (t < D) {
        float acc[16];
        #pragma unroll
        for (int b = 0; b < 16; ++b) acc[b] = 0.f;
        #pragma unroll 4
        for (int vv = 0; vv < n; ++vv) {
            float e = E[(size_t)(v0 + vv) * D + t];
            const float* ap = sal + vv * 16;
            f4 a0 = ld4(ap), a1 = ld4(ap + 4), a2 = ld4(ap + 8), a3 = ld4(ap + 12);
            #pragma unroll
            for (int b = 0; b < 4; ++b) {
                acc[b]      = fmaf(a0.v[b], e, acc[b]);
                acc[b + 4]  = fmaf(a1.v[b], e, acc[b + 4]);
                acc[b + 8]  = fmaf(a2.v[b], e, acc[b + 8]);
                acc[b + 12] = fmaf(a3.v[b], e, acc[b + 12]);
            }
        }
        #pragma unroll
        for (int b = 0; b < 16; ++b)
            partials[(size_t)c * 4800 + b * D + t] = acc[b];
    }
}

// ---------------------------------------------------------------------------
// K5/K6: two-stage reduction of partials over NC chunks, float4-wide.
__global__ void __launch_bounds__(256) k_red1(
    const float* __restrict__ partials, float* __restrict__ tmp)
{
    int o4 = blockIdx.x * 256 + threadIdx.x;   // quad index, 1200 total
    if (o4 >= 1200) return;
    int y = blockIdx.y;
    float4 s = {0.f, 0.f, 0.f, 0.f};
    for (int c = y * 32; c < y * 32 + 32; ++c) {
        float4 p = *(const float4*)(partials + (size_t)c * 4800 + o4 * 4);
        s.x += p.x; s.y += p.y; s.z += p.z; s.w += p.w;
    }
    *(float4*)(tmp + (size_t)y * 4800 + o4 * 4) = s;
}

__global__ void __launch_bounds__(256) k_red2(
    const float* __restrict__ tmp, float* __restrict__ out)
{
    int o4 = blockIdx.x * 256 + threadIdx.x;
    if (o4 >= 1200) return;
    float4 s = {0.f, 0.f, 0.f, 0.f};
    #pragma unroll
    for (int y = 0; y < 16; ++y) {
        float4 p = *(const float4*)(tmp + (size_t)y * 4800 + o4 * 4);
        s.x += p.x; s.y += p.y; s.z += p.z; s.w += p.w;
    }
    *(float4*)(out + o4 * 4) = s;
}

// ---------------------------------------------------------------------------
extern "C" void kernel_launch(void* const* d_in, const int* in_sizes, int n_in,
                              void* d_out, int out_size, void* d_ws, size_t ws_size,
                              hipStream_t stream) {
    const float* dh   = (const float*)d_in[0];
    const float* E    = (const float*)d_in[1];
    const float* Wdec = (const float*)d_in[2];
    const float* bdec = (const float*)d_in[3];
    const float* wf   = (const float*)d_in[4];
    const float* bf   = (const float*)d_in[5];
    float* out = (float*)d_out;          // enc [0,4800), alpha [4800, ...)
    float* ws  = (float*)d_ws;

    float* q_t   = ws + WS_QT;
    float* stats = ws + WS_STAT;
    float* MS    = ws + WS_MS;
    float* part  = ws + WS_PART;
    float* tmp   = ws + WS_TMP;
    float* att   = out + 4800;

    k_query<<<(D * B + 3) / 4, 256, 0, stream>>>(dh, Wdec, bdec, q_t);
    k_att<<<NB_ATT, 256, 0, stream>>>(E, q_t, wf, bf, att, stats);
    k_combine<<<B, 64, 0, stream>>>(stats, MS);
    k_awsum<<<NC, 320, 0, stream>>>(E, att, MS, part);
    k_red1<<<dim3(5, 16), 256, 0, stream>>>(part, tmp);
    k_red2<<<5, 256, 0, stream>>>(tmp, out);
}

// Round 9
// 74.367 us; speedup vs baseline: 1.2312x; 1.1713x over previous
//
#include <hip/hip_runtime.h>

constexpr int V  = 50257;   // vocab
constexpr int D  = 300;     // vocab dim
constexpr int KD = 512;     // decoder dim
constexpr int B  = 16;      // batch

constexpr int ROWS = 32;                      // rows per k_att block
constexpr int NB_ATT = (V + ROWS - 1) / ROWS; // 1571 blocks
constexpr int NT = 5;                         // 5 d-tiles of 64 (D padded 320)
constexpr int NC  = 448;                      // wsum chunks (16*28)
constexpr int RPC = 113;                      // rows per chunk, NC*RPC >= V

constexpr float NEG_HUGE = -1.0e30f;

// ws layout (float offsets)
constexpr size_t WS_QT   = 0;                              // 5120 swizzled q
constexpr size_t WS_STAT = 5120;                           // NB_ATT*32
constexpr size_t WS_MS   = WS_STAT + (size_t)NB_ATT * 32;  // 32
constexpr size_t WS_PART = WS_MS + 32;                     // NC*4800
constexpr size_t WS_TMP  = WS_PART + (size_t)NC * 4800;    // 16*4800

typedef float v2f __attribute__((ext_vector_type(2)));

struct f4 { float v[4]; };
__device__ __forceinline__ f4 ld4(const float* p) {
    float4 t = *(const float4*)p;
    return {t.x, t.y, t.z, t.w};
}

#define AS1 __attribute__((address_space(1)))
#define AS3 __attribute__((address_space(3)))
#define DPPF(x, CTRL) __int_as_float(__builtin_amdgcn_mov_dpp(__float_as_int(x), (CTRL), 0xF, 0xF, false))

// ---------------------------------------------------------------------------
// K1: q = dh @ Wdec^T + bdec, written PRE-SWIZZLED (+ zero pad to d=320) so
// k_att can DMA it straight into LDS. One wave per (d,b).
__global__ void __launch_bounds__(256) k_query(
    const float* __restrict__ dh, const float* __restrict__ Wdec,
    const float* __restrict__ bdec, float* __restrict__ q_swz)
{
    int wid  = (blockIdx.x * 256 + threadIdx.x) >> 6;
    int lane = threadIdx.x & 63;
    if (wid >= 320 * 16) return;
    int d = wid >> 4, b = wid & 15;
    float s = 0.f;
    if (d < D) {
        const float* wrow = Wdec + (size_t)d * KD;
        const float* hrow = dh + (size_t)b * KD;
        for (int k = lane; k < KD; k += 64) s += wrow[k] * hrow[k];
        #pragma unroll
        for (int off = 32; off; off >>= 1) s += __shfl_down(s, off, 64);
        s += bdec[d];
    }
    if (lane == 0) {
        int P = (d >> 1) * 8 + ((((d & 1) << 2) | (b >> 2)) ^ ((d >> 2) & 7));
        q_swz[P * 4 + (b & 3)] = (d < D) ? s : 0.f;
    }
}

// ---------------------------------------------------------------------------
// K2: att[b,v] = sum_d relu(E[v,d]+q[b,d])*wf[d] + bf.
// ROW-CONTIGUOUS staging: block owns 32 full rows of E (38.4 KB contiguous),
// staged in one linear global_load_lds burst. Single buffer; overlap comes
// from 2 blocks/CU. Compute barrier-free from LDS: thread (slot=t&15,
// rg=t>>4) handles rows {rg, rg+16}, d-slice slot*4..+3 per 64-d tile, 16 b.
// Inner math in v2f pairs -> v_pk_add/fma_f32.
__global__ void __launch_bounds__(256) k_att(
    const float* __restrict__ E, const float* __restrict__ q_swz,
    const float* __restrict__ wf, const float* __restrict__ bf,
    float* __restrict__ att, float* __restrict__ blkstats)
{
    __shared__ __align__(16) float sq[5120];    // 20.5 KB swizzled q
    __shared__ __align__(16) float seE[9632];   // 38.5 KB: 32 rows x 300 + pad
    __shared__ float sms[768];                  // stats scratch

    const int t    = threadIdx.x;
    const int slot = t & 15;
    const int rg   = t >> 4;         // 0..15
    const int v0   = blockIdx.x * ROWS;

    // --- DMA q (5 x 4KB) ---
    #pragma unroll
    for (int k = 0; k < 5; ++k)
        __builtin_amdgcn_global_load_lds((const AS1 void*)(q_swz + k * 1024 + t * 4),
                                         (AS3 void*)(sq + k * 1024 + t * 4), 16, 0, 0);
    // --- DMA E rows [v0, v0+nrow) as ONE contiguous range ---
    int nrow = V - v0; if (nrow > ROWS) nrow = ROWS;
    const int nflt = nrow * 300;
    const float* Eb = E + (size_t)v0 * 300;
    #pragma unroll
    for (int k = 0; k < 10; ++k) {
        int o = k * 1024 + t * 4;
        if (o < nflt)
            __builtin_amdgcn_global_load_lds((const AS1 void*)(Eb + o),
                                             (AS3 void*)(seE + o), 16, 0, 0);
    }
    if (t < 32) seE[9600 + t] = 0.f;   // zero pad region (avoid inf*0)

    // --- w into registers (overlaps DMA latency) ---
    f4 wreg[NT];
    #pragma unroll
    for (int k = 0; k < 4; ++k) wreg[k] = ld4(wf + k * 64 + slot * 4);
    if (slot < 11) wreg[4] = ld4(wf + 256 + slot * 4);
    else { wreg[4].v[0] = wreg[4].v[1] = wreg[4].v[2] = wreg[4].v[3] = 0.f; }
    #pragma unroll
    for (int i = 0; i < 4; ++i)
        if (256 + slot * 4 + i >= D && slot < 11) wreg[4].v[i] = 0.f;
    const float bfull = bf[0];

    // per-thread sq read offsets (r8-verified swizzle)
    int xq[2][4];
    #pragma unroll
    for (int i1 = 0; i1 < 2; ++i1)
        #pragma unroll
        for (int bq = 0; bq < 4; ++bq)
            xq[i1][bq] = slot * 64 + 4 * (((i1 << 2) | bq) ^ (slot & 7));

    v2f acc2[2][8];
    #pragma unroll
    for (int j = 0; j < 2; ++j)
        #pragma unroll
        for (int p = 0; p < 8; ++p) acc2[j][p] = (v2f){0.f, 0.f};

    __syncthreads();   // vmcnt(0)+lgkmcnt(0)+barrier: q, E, pad all visible

    // --- barrier-free compute over 5 d-tiles ---
    #pragma unroll
    for (int tt = 0; tt < NT; ++tt) {
        f4 e0 = ld4(seE + rg * 300 + tt * 64 + slot * 4);
        f4 e1 = ld4(seE + (rg + 16) * 300 + tt * 64 + slot * 4);
        const float* sqt = sq + tt * 1024;
        #pragma unroll
        for (int i = 0; i < 4; ++i) {
            float wi = wreg[tt].v[i];
            v2f w2 = {wi, wi};
            #pragma unroll
            for (int bq = 0; bq < 4; ++bq) {
                f4 qv = ld4(sqt + (i >> 1) * 32 + xq[i & 1][bq]);
                v2f qlo = {qv.v[0], qv.v[1]};
                v2f qhi = {qv.v[2], qv.v[3]};
                v2f z2  = {0.f, 0.f};
                v2f ea  = {e0.v[i], e0.v[i]};
                v2f lo0 = __builtin_elementwise_max(ea + qlo, z2);
                v2f hi0 = __builtin_elementwise_max(ea + qhi, z2);
                acc2[0][bq*2]   = __builtin_elementwise_fma(lo0, w2, acc2[0][bq*2]);
                acc2[0][bq*2+1] = __builtin_elementwise_fma(hi0, w2, acc2[0][bq*2+1]);
                v2f eb  = {e1.v[i], e1.v[i]};
                v2f lo1 = __builtin_elementwise_max(eb + qlo, z2);
                v2f hi1 = __builtin_elementwise_max(eb + qhi, z2);
                acc2[1][bq*2]   = __builtin_elementwise_fma(lo1, w2, acc2[1][bq*2]);
                acc2[1][bq*2+1] = __builtin_elementwise_fma(hi1, w2, acc2[1][bq*2+1]);
            }
        }
    }

    // unpack to scalars
    float acc[2][16];
    #pragma unroll
    for (int j = 0; j < 2; ++j)
        #pragma unroll
        for (int bq = 0; bq < 4; ++bq) {
            acc[j][bq*4+0] = acc2[j][bq*2][0];
            acc[j][bq*4+1] = acc2[j][bq*2][1];
            acc[j][bq*4+2] = acc2[j][bq*2+1][0];
            acc[j][bq*4+3] = acc2[j][bq*2+1][1];
        }

    // reduce over 16 slots: DPP xor1/xor2, compact, shfl xor4/xor8
    #pragma unroll
    for (int j = 0; j < 2; ++j)
        #pragma unroll
        for (int b = 0; b < 16; ++b) {
            float x = acc[j][b];
            x += DPPF(x, 0xB1);
            x += DPPF(x, 0x4E);
            acc[j][b] = x;
        }
    const int c = slot & 3;
    float kept[2][4];
    #pragma unroll
    for (int j = 0; j < 2; ++j)
        #pragma unroll
        for (int kk = 0; kk < 4; ++kk) {
            float x = (c == 0) ? acc[j][kk]
                    : (c == 1) ? acc[j][4 + kk]
                    : (c == 2) ? acc[j][8 + kk]
                    :            acc[j][12 + kk];
            x += __shfl_xor(x, 4, 64);
            x += __shfl_xor(x, 8, 64);
            kept[j][kk] = x;
        }

    // owners: slot bits -> c(0-1), jown(2), dup(3). Each (row,b) once.
    const int jown = (slot >> 2) & 1;
    const int dup  = slot >> 3;
    const int row  = v0 + rg + 16 * jown;
    const bool ok  = row < V;
    const int g    = rg + 16 * jown;     // 0..31
    #pragma unroll
    for (int kk2 = 0; kk2 < 2; ++kk2) {
        int b = 4 * c + (dup ? 2 : 0) + kk2;
        float x0 = jown ? kept[1][kk2]     : kept[0][kk2];
        float x1 = jown ? kept[1][2 + kk2] : kept[0][2 + kk2];
        float x  = (dup ? x1 : x0) + bfull;
        if (ok) att[(size_t)b * V + row] = x;
        sms[g * 16 + b] = ok ? x : NEG_HUGE;   // single-row partial (s=1)
    }
    __syncthreads();
    if (t < 128) {                  // level 1: merge 4 groups each
        int b = t & 15, gq = t >> 4;  // gq 0..7
        float m = NEG_HUGE;
        #pragma unroll
        for (int u = 0; u < 4; ++u) m = fmaxf(m, sms[(gq * 4 + u) * 16 + b]);
        float s = 0.f;
        #pragma unroll
        for (int u = 0; u < 4; ++u) s += __expf(sms[(gq * 4 + u) * 16 + b] - m);
        sms[512 + gq * 16 + b] = m;
        sms[640 + gq * 16 + b] = s;
    }
    __syncthreads();
    if (t < 16) {                   // level 2: merge 8
        float m = NEG_HUGE, s = 0.f;
        #pragma unroll
        for (int gq = 0; gq < 8; ++gq) {
            float mg = sms[512 + gq * 16 + t], sg = sms[640 + gq * 16 + t];
            float mn = fmaxf(m, mg);
            s = s * __expf(m - mn) + sg * __expf(mg - mn);
            m = mn;
        }
        blkstats[((size_t)blockIdx.x * 16 + t) * 2]     = m;
        blkstats[((size_t)blockIdx.x * 16 + t) * 2 + 1] = s;
    }
}

// ---------------------------------------------------------------------------
// K3: combine per-block stats -> M_b, 1/S_b
__global__ void __launch_bounds__(64) k_combine(
    const float* __restrict__ blkstats, float* __restrict__ MS)
{
    int b = blockIdx.x, lane = threadIdx.x;
    float m = NEG_HUGE;
    for (int cc = lane; cc < NB_ATT; cc += 64)
        m = fmaxf(m, blkstats[(size_t)(cc * 16 + b) * 2]);
    #pragma unroll
    for (int off = 32; off; off >>= 1) m = fmaxf(m, __shfl_xor(m, off, 64));
    float s = 0.f;
    for (int cc = lane; cc < NB_ATT; cc += 64)
        s += blkstats[(size_t)(cc * 16 + b) * 2 + 1] *
             __expf(blkstats[(size_t)(cc * 16 + b) * 2] - m);
    #pragma unroll
    for (int off = 32; off; off >>= 1) s += __shfl_xor(s, off, 64);
    if (lane == 0) { MS[b * 2] = m; MS[b * 2 + 1] = 1.f / s; }
}

// ---------------------------------------------------------------------------
// K4 (fused alpha + wsum): per chunk c of RPC rows:
//   phase 1: alpha = exp(att-M)*invS, written in place AND staged in LDS
//   phase 2: thread t<300 owns column d=t, accumulates 16 batch partials.
// E reads here are coalesced (64 lanes x 4B contiguous per row).
__global__ void __launch_bounds__(320) k_awsum(
    const float* __restrict__ E, float* __restrict__ att,
    const float* __restrict__ MS, float* __restrict__ partials)
{
    __shared__ float sal[RPC * 16];   // [vv][b]
    int c = blockIdx.x, t = threadIdx.x;
    int v0 = c * RPC;
    int n = V - v0;
    if (n > RPC) n = RPC;
    if (n < 0) n = 0;

    for (int i = t; i < RPC * 16; i += 320) {
        int b = i / RPC, vv = i - b * RPC;
        float a = 0.f;
        if (vv < n) {
            float M = MS[b * 2], invS = MS[b * 2 + 1];
            size_t gi = (size_t)b * V + v0 + vv;
            a = __expf(att[gi] - M) * invS;
            att[gi] = a;
        }
        sal[vv * 16 + b] = a;
    }
    __syncthreads();

    if (t < D) {
        float acc[16];
        #pragma unroll
        for (int b = 0; b < 16; ++b) acc[b] = 0.f;
        #pragma unroll 8
        for (int vv = 0; vv < n; ++vv) {
            float e = E[(size_t)(v0 + vv) * D + t];
            const float* ap = sal + vv * 16;
            f4 a0 = ld4(ap), a1 = ld4(ap + 4), a2 = ld4(ap + 8), a3 = ld4(ap + 12);
            #pragma unroll
            for (int b = 0; b < 4; ++b) {
                acc[b]      = fmaf(a0.v[b], e, acc[b]);
                acc[b + 4]  = fmaf(a1.v[b], e, acc[b + 4]);
                acc[b + 8]  = fmaf(a2.v[b], e, acc[b + 8]);
                acc[b + 12] = fmaf(a3.v[b], e, acc[b + 12]);
            }
        }
        #pragma unroll
        for (int b = 0; b < 16; ++b)
            partials[(size_t)c * 4800 + b * D + t] = acc[b];
    }
}

// ---------------------------------------------------------------------------
// K5/K6: two-stage reduction of partials over NC chunks, float4-wide.
__global__ void __launch_bounds__(256) k_red1(
    const float* __restrict__ partials, float* __restrict__ tmp)
{
    int o4 = blockIdx.x * 256 + threadIdx.x;   // quad index, 1200 total
    if (o4 >= 1200) return;
    int y = blockIdx.y;
    float4 s = {0.f, 0.f, 0.f, 0.f};
    for (int c = y * 28; c < y * 28 + 28; ++c) {
        float4 p = *(const float4*)(partials + (size_t)c * 4800 + o4 * 4);
        s.x += p.x; s.y += p.y; s.z += p.z; s.w += p.w;
    }
    *(float4*)(tmp + (size_t)y * 4800 + o4 * 4) = s;
}

__global__ void __launch_bounds__(256) k_red2(
    const float* __restrict__ tmp, float* __restrict__ out)
{
    int o4 = blockIdx.x * 256 + threadIdx.x;
    if (o4 >= 1200) return;
    float4 s = {0.f, 0.f, 0.f, 0.f};
    #pragma unroll
    for (int y = 0; y < 16; ++y) {
        float4 p = *(const float4*)(tmp + (size_t)y * 4800 + o4 * 4);
        s.x += p.x; s.y += p.y; s.z += p.z; s.w += p.w;
    }
    *(float4*)(out + o4 * 4) = s;
}

// ---------------------------------------------------------------------------
extern "C" void kernel_launch(void* const* d_in, const int* in_sizes, int n_in,
                              void* d_out, int out_size, void* d_ws, size_t ws_size,
                              hipStream_t stream) {
    const float* dh   = (const float*)d_in[0];
    const float* E    = (const float*)d_in[1];
    const float* Wdec = (const float*)d_in[2];
    const float* bdec = (const float*)d_in[3];
    const float* wf   = (const float*)d_in[4];
    const float* bf   = (const float*)d_in[5];
    float* out = (float*)d_out;          // enc [0,4800), alpha [4800, ...)
    float* ws  = (float*)d_ws;

    float* q_swz = ws + WS_QT;
    float* stats = ws + WS_STAT;
    float* MS    = ws + WS_MS;
    float* part  = ws + WS_PART;
    float* tmp   = ws + WS_TMP;
    float* att   = out + 4800;

    k_query<<<(320 * 16) / 4, 256, 0, stream>>>(dh, Wdec, bdec, q_swz);
    k_att<<<NB_ATT, 256, 0, stream>>>(E, q_swz, wf, bf, att, stats);
    k_combine<<<B, 64, 0, stream>>>(stats, MS);
    k_awsum<<<NC, 320, 0, stream>>>(E, att, MS, part);
    k_red1<<<dim3(5, 16), 256, 0, stream>>>(part, tmp);
    k_red2<<<5, 256, 0, stream>>>(tmp, out);
}